// Round 1
// 1717.690 us; speedup vs baseline: 3.8670x; 3.8670x over previous
//
#include <hip/hip_runtime.h>

#define NN 16384
#define MM 4096
#define DD 1024

typedef unsigned short u16;
typedef unsigned int u32;
typedef short bf16x8 __attribute__((ext_vector_type(8)));   // 8 bf16 (4 VGPRs)
typedef float f32x4 __attribute__((ext_vector_type(4)));

enum { EPI_PLAIN = 0, EPI_MASK = 1, EPI_ELU = 2 };

// diagnostic: make absmax scream a known value
__global__ void sentinel_kernel(float* out, float val) {
    if (blockIdx.x == 0 && threadIdx.x < 64) out[threadIdx.x] = val;
}

// Split-bf16 MFMA GEMM: C[R,Cc] = A[R,K] * Bt[Cc,K]^T, fp32 in/out.
// Each fp32 operand is decomposed on the fly (during LDS staging) into
// hi+lo bf16; products use 3 MFMA terms (hi*hi + hi*lo + lo*hi) into fp32
// accumulators -> ~fp32 precision at ~1/3 of bf16 MFMA rate (~690 TF ceiling
// vs 157 TF fp32 VALU). Missing lo*lo term <= 2^-14 relative per product.
// 128x128 tile, BK=32, 256 threads = 4 waves (2x2), wave tile 64x64,
// per-wave 4x4 frags of v_mfma_f32_16x16x32_bf16.
// LDS rows padded to 40 u16 (80 B, bank stride 20) -> <=2-way conflicts.
template <int EPI>
__global__ __launch_bounds__(256) void gemm_split(
    const float* __restrict__ A, const float* __restrict__ Bt,
    float* __restrict__ C, const int* __restrict__ Hm,
    int Cc, int K)
{
    __shared__ u16 sAh[128][40];
    __shared__ u16 sAl[128][40];
    __shared__ u16 sBh[128][40];
    __shared__ u16 sBl[128][40];

    const int tid = threadIdx.x;
    const int lane = tid & 63;
    const int w = tid >> 6;           // wave 0..3
    const int wm = (w >> 1) * 64;     // wave row offset in tile
    const int wn = (w & 1) * 64;      // wave col offset in tile
    const int l15 = lane & 15;
    const int l4 = lane >> 4;         // 0..3 (k-group / row-group)
    const int rowBlk = blockIdx.y * 128;
    const int colBlk = blockIdx.x * 128;
    const int sr = tid >> 1;          // staging row 0..127
    const int sk = (tid & 1) * 16;    // staging k offset {0,16} (floats)

    f32x4 acc[4][4] = {};

    union V16 { u16 u[16]; bf16x8 v[2]; };

    for (int k0 = 0; k0 < K; k0 += 32) {
        const float* pa = A + (size_t)(rowBlk + sr) * K + k0 + sk;
        const float* pb = Bt + (size_t)(colBlk + sr) * K + k0 + sk;

        V16 ah, al, bh, bl;
#pragma unroll
        for (int i = 0; i < 4; ++i) {
            const float4 va = *(const float4*)(pa + 4 * i);
            const float4 vb = *(const float4*)(pb + 4 * i);
            const float fa[4] = { va.x, va.y, va.z, va.w };
            const float fb[4] = { vb.x, vb.y, vb.z, vb.w };
#pragma unroll
            for (int j = 0; j < 4; ++j) {
                // truncating hi split; lo captures remainder exactly to 2^-14 rel
                const u32 ua = __float_as_uint(fa[j]);
                ah.u[4 * i + j] = (u16)(ua >> 16);
                const float ra = fa[j] - __uint_as_float(ua & 0xffff0000u);
                al.u[4 * i + j] = (u16)(__float_as_uint(ra) >> 16);

                const u32 ub = __float_as_uint(fb[j]);
                bh.u[4 * i + j] = (u16)(ub >> 16);
                const float rb = fb[j] - __uint_as_float(ub & 0xffff0000u);
                bl.u[4 * i + j] = (u16)(__float_as_uint(rb) >> 16);
            }
        }

        __syncthreads();              // prior iter fully consumed LDS
        *(bf16x8*)&sAh[sr][sk]     = ah.v[0];
        *(bf16x8*)&sAh[sr][sk + 8] = ah.v[1];
        *(bf16x8*)&sAl[sr][sk]     = al.v[0];
        *(bf16x8*)&sAl[sr][sk + 8] = al.v[1];
        *(bf16x8*)&sBh[sr][sk]     = bh.v[0];
        *(bf16x8*)&sBh[sr][sk + 8] = bh.v[1];
        *(bf16x8*)&sBl[sr][sk]     = bl.v[0];
        *(bf16x8*)&sBl[sr][sk + 8] = bl.v[1];
        __syncthreads();              // tile populated

        // fragment loads: contiguous 16 B -> ds_read_b128, bank stride 20 -> free
        bf16x8 a_h[4], a_l[4], b_h[4], b_l[4];
#pragma unroll
        for (int m = 0; m < 4; ++m) {
            const int r = wm + m * 16 + l15;
            a_h[m] = *(const bf16x8*)&sAh[r][l4 * 8];
            a_l[m] = *(const bf16x8*)&sAl[r][l4 * 8];
        }
#pragma unroll
        for (int n = 0; n < 4; ++n) {
            const int c = wn + n * 16 + l15;
            b_h[n] = *(const bf16x8*)&sBh[c][l4 * 8];
            b_l[n] = *(const bf16x8*)&sBl[c][l4 * 8];
        }

#pragma unroll
        for (int m = 0; m < 4; ++m)
#pragma unroll
            for (int n = 0; n < 4; ++n) {
                acc[m][n] = __builtin_amdgcn_mfma_f32_16x16x32_bf16(a_h[m], b_h[n], acc[m][n], 0, 0, 0);
                acc[m][n] = __builtin_amdgcn_mfma_f32_16x16x32_bf16(a_h[m], b_l[n], acc[m][n], 0, 0, 0);
                acc[m][n] = __builtin_amdgcn_mfma_f32_16x16x32_bf16(a_l[m], b_h[n], acc[m][n], 0, 0, 0);
            }
    }

    // epilogue: D row = (lane>>4)*4 + reg, col = lane&15 (verified m89/m91 mapping)
    const size_t ldc = (size_t)Cc;
#pragma unroll
    for (int m = 0; m < 4; ++m) {
#pragma unroll
        for (int n = 0; n < 4; ++n) {
            const int col = colBlk + wn + n * 16 + l15;
#pragma unroll
            for (int r = 0; r < 4; ++r) {
                const int row = rowBlk + wm + m * 16 + l4 * 4 + r;
                float v = acc[m][n][r];
                if constexpr (EPI == EPI_MASK) {
                    v *= 0.03125f;                               // 1/sqrt(1024)
                    if (Hm[(size_t)row * ldc + col] <= 0) v = -1e9f;
                } else if constexpr (EPI == EPI_ELU) {
                    v = v > 0.f ? v : (expf(v) - 1.f);
                }
                C[(size_t)row * ldc + col] = v;
            }
        }
    }
}

// in-place masked softmax over rows of Bm [NN x MM] (fp32); masked entries hold -1e9
__global__ __launch_bounds__(256) void softmax_rows_f32(float* __restrict__ Bm)
{
    const int row = blockIdx.x;
    const int tid = threadIdx.x;
    const int lane = tid & 63;
    const int wid = tid >> 6;
    float4* rp = reinterpret_cast<float4*>(Bm + (size_t)row * MM);  // 1024 float4

    float4 q[4];
#pragma unroll
    for (int i = 0; i < 4; ++i) q[i] = rp[i * 256 + tid];           // coalesced
    float v[16];
#pragma unroll
    for (int i = 0; i < 4; ++i) {
        v[4 * i + 0] = q[i].x; v[4 * i + 1] = q[i].y;
        v[4 * i + 2] = q[i].z; v[4 * i + 3] = q[i].w;
    }

    float mx = -3e38f;
#pragma unroll
    for (int i = 0; i < 16; ++i) mx = fmaxf(mx, v[i]);
#pragma unroll
    for (int off = 32; off >= 1; off >>= 1) mx = fmaxf(mx, __shfl_xor(mx, off));
    __shared__ float red[4];
    if (lane == 0) red[wid] = mx;
    __syncthreads();
    mx = fmaxf(fmaxf(red[0], red[1]), fmaxf(red[2], red[3]));
    __syncthreads();

    float e[16];
    float s = 0.f;
#pragma unroll
    for (int i = 0; i < 16; ++i) { e[i] = expf(v[i] - mx); s += e[i]; }
#pragma unroll
    for (int off = 32; off >= 1; off >>= 1) s += __shfl_xor(s, off);
    if (lane == 0) red[wid] = s;
    __syncthreads();
    s = red[0] + red[1] + red[2] + red[3];
    const float inv = (mx > -1e8f && s > 0.f) ? (1.0f / s) : 0.f;   // all-masked row -> 0

#pragma unroll
    for (int i = 0; i < 4; ++i) {
        q[i].x = e[4 * i + 0] * inv; q[i].y = e[4 * i + 1] * inv;
        q[i].z = e[4 * i + 2] * inv; q[i].w = e[4 * i + 3] * inv;
        rp[i * 256 + tid] = q[i];
    }
}

extern "C" void kernel_launch(void* const* d_in, const int* in_sizes, int n_in,
                              void* d_out, int out_size, void* d_ws, size_t ws_size,
                              hipStream_t stream)
{
    (void)d_ws; (void)ws_size;

    float* O = (float*)d_out;                    // [NN*DD] output 0 (fp32)
    bool ok_sizes = (n_in == 5)
        && in_sizes[0] == NN * DD && in_sizes[1] == MM * DD
        && in_sizes[2] == NN * MM
        && in_sizes[3] == DD * DD && in_sizes[4] == DD * DD;
    if (!ok_sizes) { sentinel_kernel<<<1, 64, 0, stream>>>(O, 1e6f); return; }
    if (out_size != NN * DD + NN * MM) { sentinel_kernel<<<1, 64, 0, stream>>>(O, 2e6f); return; }

    const float* x  = (const float*)d_in[0];   // [NN, DD]
    const float* er = (const float*)d_in[1];   // [MM, DD]
    const int*   Hm = (const int*)d_in[2];     // [NN, MM]
    const float* We = (const float*)d_in[3];   // [DD, DD]
    const float* Wn = (const float*)d_in[4];   // [DD, DD]

    float* Bo = O + (size_t)NN * DD;             // [NN*MM] output 1 (fp32)

    // Scratch without d_ws (all fp32):
    //   hn  -> O (64 MB region, exact fit), dead when final GEMM overwrites O
    //   he  -> x's buffer (64 MB, dead after step 1; d_in restored each launch)
    //   heT -> x's buffer + MM*DD
    float* hn  = O;
    float* he  = (float*)d_in[0];
    float* heT = he + (size_t)MM * DD;           // he+heT = 33.6 MB <= 64 MB

    dim3 blk(256);
    // 1. hn = x @ W_n^T  (last use of x)             -> O
    gemm_split<EPI_PLAIN><<<dim3(DD / 128, NN / 128), blk, 0, stream>>>(x, Wn, hn, nullptr, DD, DD);
    // 2. he = e_repr @ W_e^T                         -> x buffer
    gemm_split<EPI_PLAIN><<<dim3(DD / 128, MM / 128), blk, 0, stream>>>(er, We, he, nullptr, DD, DD);
    // 3. S = (hn @ he^T)/32, masked                  -> Bo
    gemm_split<EPI_MASK><<<dim3(MM / 128, NN / 128), blk, 0, stream>>>(hn, he, Bo, Hm, MM, DD);
    // 4. heT = W_e @ e_repr^T (= he^T)               -> x buffer + MM*DD
    gemm_split<EPI_PLAIN><<<dim3(MM / 128, DD / 128), blk, 0, stream>>>(We, er, heT, nullptr, MM, DD);
    // 5. B = softmax(S) * mask, in place (fp32)
    softmax_rows_f32<<<dim3(NN), blk, 0, stream>>>(Bo);
    // 6. out = elu(B @ heT^T)                        -> O (hn dead)
    gemm_split<EPI_ELU><<<dim3(DD / 128, NN / 128), blk, 0, stream>>>(Bo, heT, O, nullptr, DD, MM);
}

// Round 2
// 1660.931 us; speedup vs baseline: 3.9991x; 1.0342x over previous
//
#include <hip/hip_runtime.h>

#define NN 16384
#define MM 4096
#define DD 1024

typedef unsigned short u16;
typedef unsigned int u32;
typedef short bf16x8 __attribute__((ext_vector_type(8)));   // 8 bf16 (4 VGPRs)
typedef float f32x4 __attribute__((ext_vector_type(4)));

enum { EPI_MASK = 1, EPI_ELU = 2 };

// diagnostic: make absmax scream a known value
__global__ void sentinel_kernel(float* out, float val) {
    if (blockIdx.x == 0 && threadIdx.x < 64) out[threadIdx.x] = val;
}

// async 16B global->LDS (lds dest is wave-uniform base + lane*16)
__device__ __forceinline__ void gload16(const void* g, void* l) {
    __builtin_amdgcn_global_load_lds(
        (const __attribute__((address_space(1))) void*)g,
        (__attribute__((address_space(3))) void*)l, 16, 0, 0);
}

// exact split: f = bf16(hi) + ~bf16(lo), lo captures remainder (trunc)
__device__ __forceinline__ void split2(float f, u16& hi, u16& lo) {
    const u32 u = __float_as_uint(f);
    hi = (u16)(u >> 16);
    const float r = f - __uint_as_float(u & 0xffff0000u);
    lo = (u16)(__float_as_uint(r) >> 16);
}

// ---------------------------------------------------------------------------
// fp32-in -> split-bf16-planes-out GEMM (producer steps 1,2,4).
// C(hi/lo)[R,Cc] = split(A[R,K] * Bt[Cc,K]^T). 3-term split MFMA internally.
// Same proven structure as round-1 kernel; epilogue writes u16 planes.
// ---------------------------------------------------------------------------
__global__ __launch_bounds__(256) void gemm_f32_to_split(
    const float* __restrict__ A, const float* __restrict__ Bt,
    u16* __restrict__ Ch, u16* __restrict__ Cl, int Cc, int K)
{
    __shared__ u16 sAh[128][40];
    __shared__ u16 sAl[128][40];
    __shared__ u16 sBh[128][40];
    __shared__ u16 sBl[128][40];

    const int tid = threadIdx.x;
    const int lane = tid & 63;
    const int w = tid >> 6;
    const int wm = (w >> 1) * 64;
    const int wn = (w & 1) * 64;
    const int l15 = lane & 15;
    const int l4 = lane >> 4;
    const int rowBlk = blockIdx.y * 128;
    const int colBlk = blockIdx.x * 128;
    const int sr = tid >> 1;
    const int sk = (tid & 1) * 16;

    f32x4 acc[4][4] = {};
    union V16 { u16 u[16]; bf16x8 v[2]; };

    for (int k0 = 0; k0 < K; k0 += 32) {
        const float* pa = A + (size_t)(rowBlk + sr) * K + k0 + sk;
        const float* pb = Bt + (size_t)(colBlk + sr) * K + k0 + sk;

        V16 ah, al, bh, bl;
#pragma unroll
        for (int i = 0; i < 4; ++i) {
            const float4 va = *(const float4*)(pa + 4 * i);
            const float4 vb = *(const float4*)(pb + 4 * i);
            const float fa[4] = { va.x, va.y, va.z, va.w };
            const float fb[4] = { vb.x, vb.y, vb.z, vb.w };
#pragma unroll
            for (int j = 0; j < 4; ++j) {
                split2(fa[j], ah.u[4 * i + j], al.u[4 * i + j]);
                split2(fb[j], bh.u[4 * i + j], bl.u[4 * i + j]);
            }
        }

        __syncthreads();
        *(bf16x8*)&sAh[sr][sk]     = ah.v[0];
        *(bf16x8*)&sAh[sr][sk + 8] = ah.v[1];
        *(bf16x8*)&sAl[sr][sk]     = al.v[0];
        *(bf16x8*)&sAl[sr][sk + 8] = al.v[1];
        *(bf16x8*)&sBh[sr][sk]     = bh.v[0];
        *(bf16x8*)&sBh[sr][sk + 8] = bh.v[1];
        *(bf16x8*)&sBl[sr][sk]     = bl.v[0];
        *(bf16x8*)&sBl[sr][sk + 8] = bl.v[1];
        __syncthreads();

        bf16x8 a_h[4], a_l[4], b_h[4], b_l[4];
#pragma unroll
        for (int m = 0; m < 4; ++m) {
            const int r = wm + m * 16 + l15;
            a_h[m] = *(const bf16x8*)&sAh[r][l4 * 8];
            a_l[m] = *(const bf16x8*)&sAl[r][l4 * 8];
        }
#pragma unroll
        for (int n = 0; n < 4; ++n) {
            const int c = wn + n * 16 + l15;
            b_h[n] = *(const bf16x8*)&sBh[c][l4 * 8];
            b_l[n] = *(const bf16x8*)&sBl[c][l4 * 8];
        }

#pragma unroll
        for (int m = 0; m < 4; ++m)
#pragma unroll
            for (int n = 0; n < 4; ++n)
                acc[m][n] = __builtin_amdgcn_mfma_f32_16x16x32_bf16(a_h[m], b_h[n], acc[m][n], 0, 0, 0);
#pragma unroll
        for (int m = 0; m < 4; ++m)
#pragma unroll
            for (int n = 0; n < 4; ++n)
                acc[m][n] = __builtin_amdgcn_mfma_f32_16x16x32_bf16(a_h[m], b_l[n], acc[m][n], 0, 0, 0);
#pragma unroll
        for (int m = 0; m < 4; ++m)
#pragma unroll
            for (int n = 0; n < 4; ++n)
                acc[m][n] = __builtin_amdgcn_mfma_f32_16x16x32_bf16(a_l[m], b_h[n], acc[m][n], 0, 0, 0);
    }

    const size_t ldc = (size_t)Cc;
#pragma unroll
    for (int m = 0; m < 4; ++m) {
#pragma unroll
        for (int n = 0; n < 4; ++n) {
            const int col = colBlk + wn + n * 16 + l15;
#pragma unroll
            for (int r = 0; r < 4; ++r) {
                const int row = rowBlk + wm + m * 16 + l4 * 4 + r;
                u16 hi, lo;
                split2(acc[m][n][r], hi, lo);
                Ch[(size_t)row * ldc + col] = hi;
                Cl[(size_t)row * ldc + col] = lo;
            }
        }
    }
}

// ---------------------------------------------------------------------------
// Consumer GEMM: B operand always pre-split planes (global_load_lds staging,
// linear [128][32] u16 LDS rows -> conflict-free fragment reads).
// A operand: pre-split planes (ASPLIT) or fp32 converted on the fly.
// ---------------------------------------------------------------------------
template <bool ASPLIT, int EPI>
__global__ __launch_bounds__(256) void gemm_pp(
    const u16* __restrict__ Ah, const u16* __restrict__ Al,
    const float* __restrict__ Af,
    const u16* __restrict__ Bh, const u16* __restrict__ Bl,
    float* __restrict__ C, const int* __restrict__ Hm, int Cc, int K)
{
    __shared__ u16 sAh[128][32];
    __shared__ u16 sAl[128][32];
    __shared__ u16 sBh[128][32];
    __shared__ u16 sBl[128][32];

    const int tid = threadIdx.x;
    const int lane = tid & 63;
    const int w = tid >> 6;           // wave 0..3
    const int wm = (w >> 1) * 64;
    const int wn = (w & 1) * 64;
    const int l15 = lane & 15;
    const int l4 = lane >> 4;
    const int rowBlk = blockIdx.y * 128;
    const int colBlk = blockIdx.x * 128;

    // gload_lds staging: wave w owns rows [w*32, w*32+32) of each plane.
    // lane l covers row +(l>>2), 16B chunk (l&3); LDS dest = base + l*16.
    const int srow = w * 32 + (lane >> 2);
    const int scol = (lane & 3) * 8;          // u16 elements

    // fp32-A staging geometry (only !ASPLIT)
    const int fr = tid >> 1;
    const int fk = (tid & 1) * 16;

    f32x4 acc[4][4] = {};
    union V16 { u16 u[16]; bf16x8 v[2]; };

    for (int k0 = 0; k0 < K; k0 += 32) {
        V16 ah, al;
        if constexpr (!ASPLIT) {
            const float* pa = Af + (size_t)(rowBlk + fr) * K + k0 + fk;
#pragma unroll
            for (int i = 0; i < 4; ++i) {
                const float4 va = *(const float4*)(pa + 4 * i);
                const float f[4] = { va.x, va.y, va.z, va.w };
#pragma unroll
                for (int j = 0; j < 4; ++j)
                    split2(f[j], ah.u[4 * i + j], al.u[4 * i + j]);
            }
        }

        __syncthreads();              // prior iter fully consumed LDS

        {
            const size_t rb = (size_t)(colBlk + srow) * K + k0 + scol;
            gload16(Bh + rb,                 &sBh[w * 32][0]);
            gload16(Bh + rb + (size_t)16 * K, &sBh[w * 32 + 16][0]);
            gload16(Bl + rb,                 &sBl[w * 32][0]);
            gload16(Bl + rb + (size_t)16 * K, &sBl[w * 32 + 16][0]);
        }
        if constexpr (ASPLIT) {
            const size_t ra = (size_t)(rowBlk + srow) * K + k0 + scol;
            gload16(Ah + ra,                 &sAh[w * 32][0]);
            gload16(Ah + ra + (size_t)16 * K, &sAh[w * 32 + 16][0]);
            gload16(Al + ra,                 &sAl[w * 32][0]);
            gload16(Al + ra + (size_t)16 * K, &sAl[w * 32 + 16][0]);
        } else {
            *(bf16x8*)&sAh[fr][fk]     = ah.v[0];
            *(bf16x8*)&sAh[fr][fk + 8] = ah.v[1];
            *(bf16x8*)&sAl[fr][fk]     = al.v[0];
            *(bf16x8*)&sAl[fr][fk + 8] = al.v[1];
        }
        __syncthreads();              // compiler drains vmcnt+lgkmcnt before barrier

        bf16x8 a_h[4], a_l[4], b_h[4], b_l[4];
#pragma unroll
        for (int m = 0; m < 4; ++m) {
            const int r = wm + m * 16 + l15;
            a_h[m] = *(const bf16x8*)&sAh[r][l4 * 8];
            a_l[m] = *(const bf16x8*)&sAl[r][l4 * 8];
        }
#pragma unroll
        for (int n = 0; n < 4; ++n) {
            const int c = wn + n * 16 + l15;
            b_h[n] = *(const bf16x8*)&sBh[c][l4 * 8];
            b_l[n] = *(const bf16x8*)&sBl[c][l4 * 8];
        }

#pragma unroll
        for (int m = 0; m < 4; ++m)
#pragma unroll
            for (int n = 0; n < 4; ++n)
                acc[m][n] = __builtin_amdgcn_mfma_f32_16x16x32_bf16(a_h[m], b_h[n], acc[m][n], 0, 0, 0);
#pragma unroll
        for (int m = 0; m < 4; ++m)
#pragma unroll
            for (int n = 0; n < 4; ++n)
                acc[m][n] = __builtin_amdgcn_mfma_f32_16x16x32_bf16(a_h[m], b_l[n], acc[m][n], 0, 0, 0);
#pragma unroll
        for (int m = 0; m < 4; ++m)
#pragma unroll
            for (int n = 0; n < 4; ++n)
                acc[m][n] = __builtin_amdgcn_mfma_f32_16x16x32_bf16(a_l[m], b_h[n], acc[m][n], 0, 0, 0);
    }

    const size_t ldc = (size_t)Cc;
#pragma unroll
    for (int m = 0; m < 4; ++m) {
#pragma unroll
        for (int n = 0; n < 4; ++n) {
            const int col = colBlk + wn + n * 16 + l15;
#pragma unroll
            for (int r = 0; r < 4; ++r) {
                const int row = rowBlk + wm + m * 16 + l4 * 4 + r;
                float v = acc[m][n][r];
                if constexpr (EPI == EPI_MASK) {
                    v *= 0.03125f;                               // 1/sqrt(1024)
                    if (Hm[(size_t)row * ldc + col] <= 0) v = -1e9f;
                } else if constexpr (EPI == EPI_ELU) {
                    v = v > 0.f ? v : (expf(v) - 1.f);
                }
                C[(size_t)row * ldc + col] = v;
            }
        }
    }
}

// in-place masked softmax over rows of Bm [NN x MM] (fp32); masked entries hold -1e9
__global__ __launch_bounds__(256) void softmax_rows_f32(float* __restrict__ Bm)
{
    const int row = blockIdx.x;
    const int tid = threadIdx.x;
    const int lane = tid & 63;
    const int wid = tid >> 6;
    float4* rp = reinterpret_cast<float4*>(Bm + (size_t)row * MM);  // 1024 float4

    float4 q[4];
#pragma unroll
    for (int i = 0; i < 4; ++i) q[i] = rp[i * 256 + tid];           // coalesced
    float v[16];
#pragma unroll
    for (int i = 0; i < 4; ++i) {
        v[4 * i + 0] = q[i].x; v[4 * i + 1] = q[i].y;
        v[4 * i + 2] = q[i].z; v[4 * i + 3] = q[i].w;
    }

    float mx = -3e38f;
#pragma unroll
    for (int i = 0; i < 16; ++i) mx = fmaxf(mx, v[i]);
#pragma unroll
    for (int off = 32; off >= 1; off >>= 1) mx = fmaxf(mx, __shfl_xor(mx, off));
    __shared__ float red[4];
    if (lane == 0) red[wid] = mx;
    __syncthreads();
    mx = fmaxf(fmaxf(red[0], red[1]), fmaxf(red[2], red[3]));
    __syncthreads();

    float e[16];
    float s = 0.f;
#pragma unroll
    for (int i = 0; i < 16; ++i) { e[i] = expf(v[i] - mx); s += e[i]; }
#pragma unroll
    for (int off = 32; off >= 1; off >>= 1) s += __shfl_xor(s, off);
    if (lane == 0) red[wid] = s;
    __syncthreads();
    s = red[0] + red[1] + red[2] + red[3];
    const float inv = (mx > -1e8f && s > 0.f) ? (1.0f / s) : 0.f;   // all-masked row -> 0

#pragma unroll
    for (int i = 0; i < 4; ++i) {
        q[i].x = e[4 * i + 0] * inv; q[i].y = e[4 * i + 1] * inv;
        q[i].z = e[4 * i + 2] * inv; q[i].w = e[4 * i + 3] * inv;
        rp[i * 256 + tid] = q[i];
    }
}

extern "C" void kernel_launch(void* const* d_in, const int* in_sizes, int n_in,
                              void* d_out, int out_size, void* d_ws, size_t ws_size,
                              hipStream_t stream)
{
    (void)d_ws; (void)ws_size;

    float* O = (float*)d_out;                    // [NN*DD] output 0 (fp32)
    bool ok_sizes = (n_in == 5)
        && in_sizes[0] == NN * DD && in_sizes[1] == MM * DD
        && in_sizes[2] == NN * MM
        && in_sizes[3] == DD * DD && in_sizes[4] == DD * DD;
    if (!ok_sizes) { sentinel_kernel<<<1, 64, 0, stream>>>(O, 1e6f); return; }
    if (out_size != NN * DD + NN * MM) { sentinel_kernel<<<1, 64, 0, stream>>>(O, 2e6f); return; }

    const float* x  = (const float*)d_in[0];   // [NN, DD]
    const float* er = (const float*)d_in[1];   // [MM, DD]
    const int*   Hm = (const int*)d_in[2];     // [NN, MM]
    const float* We = (const float*)d_in[3];   // [DD, DD]
    const float* Wn = (const float*)d_in[4];   // [DD, DD]

    float* Bo = O + (size_t)NN * DD;             // [NN*MM] output 1 (fp32)

    // Scratch (no d_ws):
    //   hn hi/lo planes -> O region (2 x 32 MB = 64 MB exact); dead before step 6 writes O
    //   he / heT hi+lo planes -> x's buffer (4 x 8 MB = 32 MB <= 64 MB; x dead after step 1)
    u16* hn_h  = (u16*)O;
    u16* hn_l  = hn_h + (size_t)NN * DD;
    u16* he_h  = (u16*)d_in[0];
    u16* he_l  = he_h + (size_t)MM * DD;
    u16* heT_h = he_l + (size_t)MM * DD;
    u16* heT_l = heT_h + (size_t)DD * MM;

    dim3 blk(256);
    // 1. hn = x @ Wn^T -> split planes in O       (last use of x)
    gemm_f32_to_split<<<dim3(DD / 128, NN / 128), blk, 0, stream>>>(x, Wn, hn_h, hn_l, DD, DD);
    // 2. he = e_repr @ We^T -> split planes in x buffer
    gemm_f32_to_split<<<dim3(DD / 128, MM / 128), blk, 0, stream>>>(er, We, he_h, he_l, DD, DD);
    // 3. heT = We @ e_repr^T (= he^T) -> split planes
    gemm_f32_to_split<<<dim3(MM / 128, DD / 128), blk, 0, stream>>>(We, er, heT_h, heT_l, MM, DD);
    // 4. S = (hn @ he^T)/32, masked -> Bo (both operands pre-split)
    gemm_pp<true, EPI_MASK><<<dim3(MM / 128, NN / 128), blk, 0, stream>>>(
        hn_h, hn_l, nullptr, he_h, he_l, Bo, Hm, MM, DD);
    // 5. B = softmax(S) * mask, in place (fp32)
    softmax_rows_f32<<<dim3(NN), blk, 0, stream>>>(Bo);
    // 6. out = elu(B @ heT^T) -> O (hn planes dead; A converted on the fly)
    gemm_pp<false, EPI_ELU><<<dim3(DD / 128, NN / 128), blk, 0, stream>>>(
        nullptr, nullptr, Bo, heT_h, heT_l, O, nullptr, DD, MM);
}

// Round 4
// 1452.536 us; speedup vs baseline: 4.5729x; 1.1435x over previous
//
#include <hip/hip_runtime.h>

#define NN 16384
#define MM 4096
#define DD 1024

typedef unsigned short u16;
typedef unsigned int u32;
typedef short bf16x8 __attribute__((ext_vector_type(8)));   // 8 bf16 (4 VGPRs)
typedef float f32x4 __attribute__((ext_vector_type(4)));

enum { EPI_MASK = 1, EPI_ELU = 2 };

// diagnostic: make absmax scream a known value
__global__ void sentinel_kernel(float* out, float val) {
    if (blockIdx.x == 0 && threadIdx.x < 64) out[threadIdx.x] = val;
}

// async 16B global->LDS (lds dest is wave-uniform base + lane*16)
__device__ __forceinline__ void gload16(const void* g, void* l) {
    __builtin_amdgcn_global_load_lds(
        (const __attribute__((address_space(1))) void*)g,
        (__attribute__((address_space(3))) void*)l, 16, 0, 0);
}

// exact split: f = bf16(hi) + ~bf16(lo), lo captures remainder (trunc)
__device__ __forceinline__ void split2(float f, u16& hi, u16& lo) {
    const u32 u = __float_as_uint(f);
    hi = (u16)(u >> 16);
    const float r = f - __uint_as_float(u & 0xffff0000u);
    lo = (u16)(__float_as_uint(r) >> 16);
}

// fp32 -> bf16 round-to-nearest-even
__device__ __forceinline__ u16 f2bf_rtne(float f) {
    const u32 u = __float_as_uint(f);
    return (u16)((u + 0x7FFFu + ((u >> 16) & 1u)) >> 16);
}

// ---------------------------------------------------------------------------
// fp32-in -> split-bf16-planes-out GEMM (producer steps 1,2,3).
// C(hi/lo)[R,Cc] = split(A[R,K] * Bt[Cc,K]^T). 3-term split MFMA internally.
// Cl may be nullptr (hi-only output, used for heT which feeds a bf16 GEMM).
// ---------------------------------------------------------------------------
__global__ __launch_bounds__(256) void gemm_f32_to_split(
    const float* __restrict__ A, const float* __restrict__ Bt,
    u16* __restrict__ Ch, u16* __restrict__ Cl, int Cc, int K)
{
    __shared__ u16 sAh[128][40];
    __shared__ u16 sAl[128][40];
    __shared__ u16 sBh[128][40];
    __shared__ u16 sBl[128][40];

    const int tid = threadIdx.x;
    const int lane = tid & 63;
    const int w = tid >> 6;
    const int wm = (w >> 1) * 64;
    const int wn = (w & 1) * 64;
    const int l15 = lane & 15;
    const int l4 = lane >> 4;
    const int rowBlk = blockIdx.y * 128;
    const int colBlk = blockIdx.x * 128;
    const int sr = tid >> 1;
    const int sk = (tid & 1) * 16;

    f32x4 acc[4][4] = {};
    union V16 { u16 u[16]; bf16x8 v[2]; };

    for (int k0 = 0; k0 < K; k0 += 32) {
        const float* pa = A + (size_t)(rowBlk + sr) * K + k0 + sk;
        const float* pb = Bt + (size_t)(colBlk + sr) * K + k0 + sk;

        V16 ah, al, bh, bl;
#pragma unroll
        for (int i = 0; i < 4; ++i) {
            const float4 va = *(const float4*)(pa + 4 * i);
            const float4 vb = *(const float4*)(pb + 4 * i);
            const float fa[4] = { va.x, va.y, va.z, va.w };
            const float fb[4] = { vb.x, vb.y, vb.z, vb.w };
#pragma unroll
            for (int j = 0; j < 4; ++j) {
                split2(fa[j], ah.u[4 * i + j], al.u[4 * i + j]);
                split2(fb[j], bh.u[4 * i + j], bl.u[4 * i + j]);
            }
        }

        __syncthreads();
        *(bf16x8*)&sAh[sr][sk]     = ah.v[0];
        *(bf16x8*)&sAh[sr][sk + 8] = ah.v[1];
        *(bf16x8*)&sAl[sr][sk]     = al.v[0];
        *(bf16x8*)&sAl[sr][sk + 8] = al.v[1];
        *(bf16x8*)&sBh[sr][sk]     = bh.v[0];
        *(bf16x8*)&sBh[sr][sk + 8] = bh.v[1];
        *(bf16x8*)&sBl[sr][sk]     = bl.v[0];
        *(bf16x8*)&sBl[sr][sk + 8] = bl.v[1];
        __syncthreads();

        bf16x8 a_h[4], a_l[4], b_h[4], b_l[4];
#pragma unroll
        for (int m = 0; m < 4; ++m) {
            const int r = wm + m * 16 + l15;
            a_h[m] = *(const bf16x8*)&sAh[r][l4 * 8];
            a_l[m] = *(const bf16x8*)&sAl[r][l4 * 8];
        }
#pragma unroll
        for (int n = 0; n < 4; ++n) {
            const int c = wn + n * 16 + l15;
            b_h[n] = *(const bf16x8*)&sBh[c][l4 * 8];
            b_l[n] = *(const bf16x8*)&sBl[c][l4 * 8];
        }

#pragma unroll
        for (int m = 0; m < 4; ++m)
#pragma unroll
            for (int n = 0; n < 4; ++n)
                acc[m][n] = __builtin_amdgcn_mfma_f32_16x16x32_bf16(a_h[m], b_h[n], acc[m][n], 0, 0, 0);
#pragma unroll
        for (int m = 0; m < 4; ++m)
#pragma unroll
            for (int n = 0; n < 4; ++n)
                acc[m][n] = __builtin_amdgcn_mfma_f32_16x16x32_bf16(a_h[m], b_l[n], acc[m][n], 0, 0, 0);
#pragma unroll
        for (int m = 0; m < 4; ++m)
#pragma unroll
            for (int n = 0; n < 4; ++n)
                acc[m][n] = __builtin_amdgcn_mfma_f32_16x16x32_bf16(a_l[m], b_h[n], acc[m][n], 0, 0, 0);
    }

    const size_t ldc = (size_t)Cc;
#pragma unroll
    for (int m = 0; m < 4; ++m) {
#pragma unroll
        for (int n = 0; n < 4; ++n) {
            const int col = colBlk + wn + n * 16 + l15;
#pragma unroll
            for (int r = 0; r < 4; ++r) {
                const int row = rowBlk + wm + m * 16 + l4 * 4 + r;
                u16 hi, lo;
                split2(acc[m][n][r], hi, lo);
                Ch[(size_t)row * ldc + col] = hi;
                if (Cl) Cl[(size_t)row * ldc + col] = lo;
            }
        }
    }
}

// ---------------------------------------------------------------------------
// Step 4: both operands pre-split planes, global_load_lds staging with
// XOR-swizzled chunk layout (linear LDS dest + inverse-swizzled global source
// + swizzled read; XOR terms are lane-constant). 3-term split MFMA, mask epi.
// LDS tile [128][32] u16; chunk(16B) index c stored at c ^ ((row>>1)&3):
// fragment reads become 2-way bank aliasing (free) instead of 8-way.
// ---------------------------------------------------------------------------
__global__ __launch_bounds__(256) void gemm_split_mask(
    const u16* __restrict__ Ah, const u16* __restrict__ Al,
    const u16* __restrict__ Bh, const u16* __restrict__ Bl,
    float* __restrict__ C, const int* __restrict__ Hm, int Cc, int K)
{
    __shared__ u16 sAh[128][32];
    __shared__ u16 sAl[128][32];
    __shared__ u16 sBh[128][32];
    __shared__ u16 sBl[128][32];

    const int tid = threadIdx.x;
    const int lane = tid & 63;
    const int w = tid >> 6;           // wave 0..3
    const int wm = (w >> 1) * 64;
    const int wn = (w & 1) * 64;
    const int l15 = lane & 15;
    const int l4 = lane >> 4;
    const int rowBlk = blockIdx.y * 128;
    const int colBlk = blockIdx.x * 128;

    // staging: wave w owns rows [w*32, w*32+32); lane l covers row +(l>>2),
    // LDS position chunk (l&3); fetch global chunk (l&3)^((srow>>1)&3) = (l&3)^((l>>3)&3)
    const int srow = w * 32 + (lane >> 2);
    const int scol = ((lane & 3) ^ ((lane >> 3) & 3)) * 8;    // u16 elements
    // fragment read: want chunk l4 of row r -> stored at l4^((r>>1)&3) = l4^((l15>>1)&3)
    const int rchunk = (l4 ^ ((l15 >> 1) & 3)) * 8;

    f32x4 acc[4][4] = {};

    for (int k0 = 0; k0 < K; k0 += 32) {
        __syncthreads();              // prior iter fully consumed LDS
        const size_t ra = (size_t)(rowBlk + srow) * K + k0 + scol;
        const size_t rb = (size_t)(colBlk + srow) * K + k0 + scol;
        gload16(Ah + ra,                  &sAh[w * 32][0]);
        gload16(Ah + ra + (size_t)16 * K, &sAh[w * 32 + 16][0]);
        gload16(Al + ra,                  &sAl[w * 32][0]);
        gload16(Al + ra + (size_t)16 * K, &sAl[w * 32 + 16][0]);
        gload16(Bh + rb,                  &sBh[w * 32][0]);
        gload16(Bh + rb + (size_t)16 * K, &sBh[w * 32 + 16][0]);
        gload16(Bl + rb,                  &sBl[w * 32][0]);
        gload16(Bl + rb + (size_t)16 * K, &sBl[w * 32 + 16][0]);
        __syncthreads();              // compiler drains vmcnt before barrier

        bf16x8 a_h[4], a_l[4], b_h[4], b_l[4];
#pragma unroll
        for (int m = 0; m < 4; ++m) {
            const int r = wm + m * 16 + l15;
            a_h[m] = *(const bf16x8*)&sAh[r][rchunk];
            a_l[m] = *(const bf16x8*)&sAl[r][rchunk];
        }
#pragma unroll
        for (int n = 0; n < 4; ++n) {
            const int c = wn + n * 16 + l15;
            b_h[n] = *(const bf16x8*)&sBh[c][rchunk];
            b_l[n] = *(const bf16x8*)&sBl[c][rchunk];
        }

#pragma unroll
        for (int m = 0; m < 4; ++m)
#pragma unroll
            for (int n = 0; n < 4; ++n)
                acc[m][n] = __builtin_amdgcn_mfma_f32_16x16x32_bf16(a_h[m], b_h[n], acc[m][n], 0, 0, 0);
#pragma unroll
        for (int m = 0; m < 4; ++m)
#pragma unroll
            for (int n = 0; n < 4; ++n)
                acc[m][n] = __builtin_amdgcn_mfma_f32_16x16x32_bf16(a_h[m], b_l[n], acc[m][n], 0, 0, 0);
#pragma unroll
        for (int m = 0; m < 4; ++m)
#pragma unroll
            for (int n = 0; n < 4; ++n)
                acc[m][n] = __builtin_amdgcn_mfma_f32_16x16x32_bf16(a_l[m], b_h[n], acc[m][n], 0, 0, 0);
    }

    const size_t ldc = (size_t)Cc;
#pragma unroll
    for (int m = 0; m < 4; ++m) {
#pragma unroll
        for (int n = 0; n < 4; ++n) {
            const int col = colBlk + wn + n * 16 + l15;
#pragma unroll
            for (int r = 0; r < 4; ++r) {
                const int row = rowBlk + wm + m * 16 + l4 * 4 + r;
                float v = acc[m][n][r] * 0.03125f;               // 1/sqrt(1024)
                if (Hm[(size_t)row * ldc + col] <= 0) v = -1e9f;
                C[(size_t)row * ldc + col] = v;
            }
        }
    }
}

// ---------------------------------------------------------------------------
// Step 6: pure bf16 1-term GEMM (B probs @ heT^T), elu epilogue.
// Both operands bf16 via global_load_lds, swizzled layout as above.
// PV in bf16 adds ~6e-5 abs error (B in [0,1], sum(B)=1) -- far below budget.
// ---------------------------------------------------------------------------
__global__ __launch_bounds__(256) void gemm_bf16_elu(
    const u16* __restrict__ A, const u16* __restrict__ Bt,
    float* __restrict__ C, int Cc, int K)
{
    __shared__ u16 sA[128][32];
    __shared__ u16 sB[128][32];

    const int tid = threadIdx.x;
    const int lane = tid & 63;
    const int w = tid >> 6;
    const int wm = (w >> 1) * 64;
    const int wn = (w & 1) * 64;
    const int l15 = lane & 15;
    const int l4 = lane >> 4;
    const int rowBlk = blockIdx.y * 128;
    const int colBlk = blockIdx.x * 128;

    const int srow = w * 32 + (lane >> 2);
    const int scol = ((lane & 3) ^ ((lane >> 3) & 3)) * 8;
    const int rchunk = (l4 ^ ((l15 >> 1) & 3)) * 8;

    f32x4 acc[4][4] = {};

    for (int k0 = 0; k0 < K; k0 += 32) {
        __syncthreads();
        const size_t ra = (size_t)(rowBlk + srow) * K + k0 + scol;
        const size_t rb = (size_t)(colBlk + srow) * K + k0 + scol;
        gload16(A + ra,                   &sA[w * 32][0]);
        gload16(A + ra + (size_t)16 * K,  &sA[w * 32 + 16][0]);
        gload16(Bt + rb,                  &sB[w * 32][0]);
        gload16(Bt + rb + (size_t)16 * K, &sB[w * 32 + 16][0]);
        __syncthreads();

        bf16x8 a[4], b[4];
#pragma unroll
        for (int m = 0; m < 4; ++m)
            a[m] = *(const bf16x8*)&sA[wm + m * 16 + l15][rchunk];
#pragma unroll
        for (int n = 0; n < 4; ++n)
            b[n] = *(const bf16x8*)&sB[wn + n * 16 + l15][rchunk];

#pragma unroll
        for (int m = 0; m < 4; ++m)
#pragma unroll
            for (int n = 0; n < 4; ++n)
                acc[m][n] = __builtin_amdgcn_mfma_f32_16x16x32_bf16(a[m], b[n], acc[m][n], 0, 0, 0);
    }

    const size_t ldc = (size_t)Cc;
#pragma unroll
    for (int m = 0; m < 4; ++m) {
#pragma unroll
        for (int n = 0; n < 4; ++n) {
            const int col = colBlk + wn + n * 16 + l15;
#pragma unroll
            for (int r = 0; r < 4; ++r) {
                const int row = rowBlk + wm + m * 16 + l4 * 4 + r;
                float v = acc[m][n][r];
                v = v > 0.f ? v : (expf(v) - 1.f);
                C[(size_t)row * ldc + col] = v;
            }
        }
    }
}

// in-place masked softmax over rows of Bm [NN x MM] (fp32); masked entries
// hold -1e9. Also emits a bf16 (RTNE) copy of the probs for the PV GEMM.
__global__ __launch_bounds__(256) void softmax_rows_f32(
    float* __restrict__ Bm, u16* __restrict__ B16)
{
    const int row = blockIdx.x;
    const int tid = threadIdx.x;
    const int lane = tid & 63;
    const int wid = tid >> 6;
    float4* rp = reinterpret_cast<float4*>(Bm + (size_t)row * MM);  // 1024 float4

    float4 q[4];
#pragma unroll
    for (int i = 0; i < 4; ++i) q[i] = rp[i * 256 + tid];           // coalesced
    float v[16];
#pragma unroll
    for (int i = 0; i < 4; ++i) {
        v[4 * i + 0] = q[i].x; v[4 * i + 1] = q[i].y;
        v[4 * i + 2] = q[i].z; v[4 * i + 3] = q[i].w;
    }

    float mx = -3e38f;
#pragma unroll
    for (int i = 0; i < 16; ++i) mx = fmaxf(mx, v[i]);
#pragma unroll
    for (int off = 32; off >= 1; off >>= 1) mx = fmaxf(mx, __shfl_xor(mx, off));
    __shared__ float red[4];
    if (lane == 0) red[wid] = mx;
    __syncthreads();
    mx = fmaxf(fmaxf(red[0], red[1]), fmaxf(red[2], red[3]));
    __syncthreads();

    float e[16];
    float s = 0.f;
#pragma unroll
    for (int i = 0; i < 16; ++i) { e[i] = expf(v[i] - mx); s += e[i]; }
#pragma unroll
    for (int off = 32; off >= 1; off >>= 1) s += __shfl_xor(s, off);
    if (lane == 0) red[wid] = s;
    __syncthreads();
    s = red[0] + red[1] + red[2] + red[3];
    const float inv = (mx > -1e8f && s > 0.f) ? (1.0f / s) : 0.f;   // all-masked row -> 0

    ushort4* hp = reinterpret_cast<ushort4*>(B16 + (size_t)row * MM);
#pragma unroll
    for (int i = 0; i < 4; ++i) {
        q[i].x = e[4 * i + 0] * inv; q[i].y = e[4 * i + 1] * inv;
        q[i].z = e[4 * i + 2] * inv; q[i].w = e[4 * i + 3] * inv;
        rp[i * 256 + tid] = q[i];
        ushort4 h;
        h.x = f2bf_rtne(q[i].x); h.y = f2bf_rtne(q[i].y);
        h.z = f2bf_rtne(q[i].z); h.w = f2bf_rtne(q[i].w);
        hp[i * 256 + tid] = h;
    }
}

extern "C" void kernel_launch(void* const* d_in, const int* in_sizes, int n_in,
                              void* d_out, int out_size, void* d_ws, size_t ws_size,
                              hipStream_t stream)
{
    (void)d_ws; (void)ws_size;

    float* O = (float*)d_out;                    // [NN*DD] output 0 (fp32)
    bool ok_sizes = (n_in == 5)
        && in_sizes[0] == NN * DD && in_sizes[1] == MM * DD
        && in_sizes[2] == NN * MM
        && in_sizes[3] == DD * DD && in_sizes[4] == DD * DD;
    if (!ok_sizes) { sentinel_kernel<<<1, 64, 0, stream>>>(O, 1e6f); return; }
    if (out_size != NN * DD + NN * MM) { sentinel_kernel<<<1, 64, 0, stream>>>(O, 2e6f); return; }

    const float* x  = (const float*)d_in[0];   // [NN, DD]
    const float* er = (const float*)d_in[1];   // [MM, DD]
    const int*   Hm = (const int*)d_in[2];     // [NN, MM]
    const float* We = (const float*)d_in[3];   // [DD, DD]
    const float* Wn = (const float*)d_in[4];   // [DD, DD]

    float* Bo = O + (size_t)NN * DD;             // [NN*MM] output 1 (fp32)

    // Scratch (no d_ws; inputs are restored by the harness each launch):
    //   hn hi/lo planes -> O region (64 MB exact); dead before step 6 writes O
    //   he hi+lo, heT hi -> x's buffer (24 MB <= 64 MB; x dead after step 1)
    //   B bf16 probs -> Hm's buffer (128 MB <= 256 MB; Hm dead after step 4)
    u16* hn_h  = (u16*)O;
    u16* hn_l  = hn_h + (size_t)NN * DD;
    u16* he_h  = (u16*)d_in[0];
    u16* he_l  = he_h + (size_t)MM * DD;
    u16* heT_h = he_l + (size_t)MM * DD;
    u16* B16   = (u16*)d_in[2];

    dim3 blk(256);
    // 1. hn = x @ Wn^T -> split planes in O       (last use of x)
    gemm_f32_to_split<<<dim3(DD / 128, NN / 128), blk, 0, stream>>>(x, Wn, hn_h, hn_l, DD, DD);
    // 2. he = e_repr @ We^T -> split planes in x buffer
    gemm_f32_to_split<<<dim3(DD / 128, MM / 128), blk, 0, stream>>>(er, We, he_h, he_l, DD, DD);
    // 3. heT = We @ e_repr^T (= he^T) -> hi plane only (feeds bf16 PV GEMM)
    gemm_f32_to_split<<<dim3(MM / 128, DD / 128), blk, 0, stream>>>(We, er, heT_h, nullptr, MM, DD);
    // 4. S = (hn @ he^T)/32, masked -> Bo (both operands pre-split; last use of Hm)
    gemm_split_mask<<<dim3(MM / 128, NN / 128), blk, 0, stream>>>(
        hn_h, hn_l, he_h, he_l, Bo, Hm, MM, DD);
    // 5. B = softmax(S) * mask, in place (fp32) + bf16 copy into Hm buffer
    softmax_rows_f32<<<dim3(NN), blk, 0, stream>>>(Bo, B16);
    // 6. out = elu(B16 @ heT^T) -> O (hn planes dead; pure bf16, 1-term)
    gemm_bf16_elu<<<dim3(DD / 128, NN / 128), blk, 0, stream>>>(B16, heT_h, O, DD, MM);
}

// Round 5
// 1430.692 us; speedup vs baseline: 4.6427x; 1.0153x over previous
//
#include <hip/hip_runtime.h>

#define NN 16384
#define MM 4096
#define DD 1024

typedef unsigned short u16;
typedef unsigned int u32;
typedef short bf16x8 __attribute__((ext_vector_type(8)));   // 8 bf16 (4 VGPRs)
typedef float f32x4 __attribute__((ext_vector_type(4)));

enum { EPI_SPLIT = 0, EPI_SPLITH = 1, EPI_MASK = 2 };

// diagnostic: make absmax scream a known value
__global__ void sentinel_kernel(float* out, float val) {
    if (blockIdx.x == 0 && threadIdx.x < 64) out[threadIdx.x] = val;
}

// async 16B global->LDS (lds dest is wave-uniform base + lane*16)
__device__ __forceinline__ void gload16(const void* g, void* l) {
    __builtin_amdgcn_global_load_lds(
        (const __attribute__((address_space(1))) void*)g,
        (__attribute__((address_space(3))) void*)l, 16, 0, 0);
}

// exact split: f = bf16(hi) + ~bf16(lo), lo captures remainder (trunc)
__device__ __forceinline__ void split2(float f, u16& hi, u16& lo) {
    const u32 u = __float_as_uint(f);
    hi = (u16)(u >> 16);
    const float r = f - __uint_as_float(u & 0xffff0000u);
    lo = (u16)(__float_as_uint(r) >> 16);
}

// fp32 -> bf16 round-to-nearest-even
__device__ __forceinline__ u16 f2bf_rtne(float f) {
    const u32 u = __float_as_uint(f);
    return (u16)((u + 0x7FFFu + ((u >> 16) & 1u)) >> 16);
}

// ---------------------------------------------------------------------------
// one-time elementwise split of an fp32 array into hi/lo bf16 planes
// ---------------------------------------------------------------------------
__global__ __launch_bounds__(256) void split_f32(
    const float* __restrict__ src, u16* __restrict__ hi, u16* __restrict__ lo,
    long n4)
{
    long i = (long)blockIdx.x * 256 + threadIdx.x;
    const long stride = (long)gridDim.x * 256;
    for (; i < n4; i += stride) {
        const float4 v = ((const float4*)src)[i];
        ushort4 h, l;
        split2(v.x, h.x, l.x); split2(v.y, h.y, l.y);
        split2(v.z, h.z, l.z); split2(v.w, h.w, l.w);
        ((ushort4*)hi)[i] = h;
        ((ushort4*)lo)[i] = l;
    }
}

// ---------------------------------------------------------------------------
// Pre-split 3-term GEMM: C[R,Cc] = (Ah+Al)[R,K] * (Bh+Bl)[Cc,K]^T (hh+hl+lh).
// Double-buffered LDS, ONE barrier per K-step: issue next tile's
// global_load_lds BEFORE reading/computing current tile, so HBM/L2 latency
// hides under ds_read+MFMA (T3 minimum-2-phase). Swizzled chunk layout
// (linear LDS dest + inverse-swizzled global source + swizzled read) keeps
// fragment ds_read_b128 conflict-free (verified: SQ_LDS_BANK_CONFLICT = 0).
// Epilogues: SPLIT (hi+lo planes), SPLITH (hi only), MASK (fp32 scores).
// ---------------------------------------------------------------------------
template <int EPI>
__global__ __launch_bounds__(256) void gemm_ps3(
    const u16* __restrict__ Ah, const u16* __restrict__ Al,
    const u16* __restrict__ Bh, const u16* __restrict__ Bl,
    u16* __restrict__ Ch, u16* __restrict__ Cl,
    float* __restrict__ Cf, const int* __restrict__ Hm,
    int Cc, int K)
{
    __shared__ u16 sAh[2][128][32];
    __shared__ u16 sAl[2][128][32];
    __shared__ u16 sBh[2][128][32];
    __shared__ u16 sBl[2][128][32];

    const int tid = threadIdx.x;
    const int lane = tid & 63;
    const int w = tid >> 6;           // wave 0..3
    const int wm = (w >> 1) * 64;
    const int wn = (w & 1) * 64;
    const int l15 = lane & 15;
    const int l4 = lane >> 4;
    const int rowBlk = blockIdx.y * 128;
    const int colBlk = blockIdx.x * 128;

    // staging: wave w owns rows [w*32, w*32+32); lane l covers row +(l>>2),
    // LDS chunk (l&3); fetch global chunk (l&3)^((srow>>1)&3) = (l&3)^((l>>3)&3)
    const int srow = w * 32 + (lane >> 2);
    const int scol = ((lane & 3) ^ ((lane >> 3) & 3)) * 8;    // u16 elements
    // fragment read: chunk l4 of row r stored at l4^((r>>1)&3) = l4^((l15>>1)&3)
    const int rchunk = (l4 ^ ((l15 >> 1) & 3)) * 8;

    f32x4 acc[4][4] = {};

    auto stage = [&](int b, int k0) {
        const size_t ra = (size_t)(rowBlk + srow) * K + k0 + scol;
        const size_t rb = (size_t)(colBlk + srow) * K + k0 + scol;
        gload16(Ah + ra,                  &sAh[b][w * 32][0]);
        gload16(Ah + ra + (size_t)16 * K, &sAh[b][w * 32 + 16][0]);
        gload16(Al + ra,                  &sAl[b][w * 32][0]);
        gload16(Al + ra + (size_t)16 * K, &sAl[b][w * 32 + 16][0]);
        gload16(Bh + rb,                  &sBh[b][w * 32][0]);
        gload16(Bh + rb + (size_t)16 * K, &sBh[b][w * 32 + 16][0]);
        gload16(Bl + rb,                  &sBl[b][w * 32][0]);
        gload16(Bl + rb + (size_t)16 * K, &sBl[b][w * 32 + 16][0]);
    };

    stage(0, 0);
    __syncthreads();                  // buf0 landed (vmcnt(0) implied)
    int cur = 0;

    for (int k0 = 0; k0 < K; k0 += 32) {
        if (k0 + 32 < K) stage(cur ^ 1, k0 + 32);   // prefetch next tile

        bf16x8 a_h[4], a_l[4], b_h[4], b_l[4];
#pragma unroll
        for (int m = 0; m < 4; ++m) {
            const int r = wm + m * 16 + l15;
            a_h[m] = *(const bf16x8*)&sAh[cur][r][rchunk];
            a_l[m] = *(const bf16x8*)&sAl[cur][r][rchunk];
        }
#pragma unroll
        for (int n = 0; n < 4; ++n) {
            const int c = wn + n * 16 + l15;
            b_h[n] = *(const bf16x8*)&sBh[cur][c][rchunk];
            b_l[n] = *(const bf16x8*)&sBl[cur][c][rchunk];
        }

#pragma unroll
        for (int m = 0; m < 4; ++m)
#pragma unroll
            for (int n = 0; n < 4; ++n)
                acc[m][n] = __builtin_amdgcn_mfma_f32_16x16x32_bf16(a_h[m], b_h[n], acc[m][n], 0, 0, 0);
#pragma unroll
        for (int m = 0; m < 4; ++m)
#pragma unroll
            for (int n = 0; n < 4; ++n)
                acc[m][n] = __builtin_amdgcn_mfma_f32_16x16x32_bf16(a_h[m], b_l[n], acc[m][n], 0, 0, 0);
#pragma unroll
        for (int m = 0; m < 4; ++m)
#pragma unroll
            for (int n = 0; n < 4; ++n)
                acc[m][n] = __builtin_amdgcn_mfma_f32_16x16x32_bf16(a_l[m], b_h[n], acc[m][n], 0, 0, 0);

        __syncthreads();              // drains vmcnt (prefetch landed) + reads done
        cur ^= 1;
    }

    const size_t ldc = (size_t)Cc;
#pragma unroll
    for (int m = 0; m < 4; ++m) {
#pragma unroll
        for (int n = 0; n < 4; ++n) {
            const int col = colBlk + wn + n * 16 + l15;
#pragma unroll
            for (int r = 0; r < 4; ++r) {
                const int row = rowBlk + wm + m * 16 + l4 * 4 + r;
                const size_t idx = (size_t)row * ldc + col;
                if constexpr (EPI == EPI_MASK) {
                    float v = acc[m][n][r] * 0.03125f;           // 1/sqrt(1024)
                    if (Hm[idx] <= 0) v = -1e9f;
                    Cf[idx] = v;
                } else {
                    u16 hi, lo;
                    split2(acc[m][n][r], hi, lo);
                    Ch[idx] = hi;
                    if constexpr (EPI == EPI_SPLIT) Cl[idx] = lo;
                }
            }
        }
    }
}

// ---------------------------------------------------------------------------
// Step 6: pure bf16 1-term GEMM (B probs @ heT^T), elu epilogue.
// Same dbuf single-barrier loop and swizzle. PV in bf16 adds ~6e-5 abs error.
// ---------------------------------------------------------------------------
__global__ __launch_bounds__(256) void gemm_bf16_elu(
    const u16* __restrict__ A, const u16* __restrict__ Bt,
    float* __restrict__ C, int Cc, int K)
{
    __shared__ u16 sA[2][128][32];
    __shared__ u16 sB[2][128][32];

    const int tid = threadIdx.x;
    const int lane = tid & 63;
    const int w = tid >> 6;
    const int wm = (w >> 1) * 64;
    const int wn = (w & 1) * 64;
    const int l15 = lane & 15;
    const int l4 = lane >> 4;
    const int rowBlk = blockIdx.y * 128;
    const int colBlk = blockIdx.x * 128;

    const int srow = w * 32 + (lane >> 2);
    const int scol = ((lane & 3) ^ ((lane >> 3) & 3)) * 8;
    const int rchunk = (l4 ^ ((l15 >> 1) & 3)) * 8;

    f32x4 acc[4][4] = {};

    auto stage = [&](int b, int k0) {
        const size_t ra = (size_t)(rowBlk + srow) * K + k0 + scol;
        const size_t rb = (size_t)(colBlk + srow) * K + k0 + scol;
        gload16(A + ra,                   &sA[b][w * 32][0]);
        gload16(A + ra + (size_t)16 * K,  &sA[b][w * 32 + 16][0]);
        gload16(Bt + rb,                  &sB[b][w * 32][0]);
        gload16(Bt + rb + (size_t)16 * K, &sB[b][w * 32 + 16][0]);
    };

    stage(0, 0);
    __syncthreads();
    int cur = 0;

    for (int k0 = 0; k0 < K; k0 += 32) {
        if (k0 + 32 < K) stage(cur ^ 1, k0 + 32);

        bf16x8 a[4], b[4];
#pragma unroll
        for (int m = 0; m < 4; ++m)
            a[m] = *(const bf16x8*)&sA[cur][wm + m * 16 + l15][rchunk];
#pragma unroll
        for (int n = 0; n < 4; ++n)
            b[n] = *(const bf16x8*)&sB[cur][wn + n * 16 + l15][rchunk];

#pragma unroll
        for (int m = 0; m < 4; ++m)
#pragma unroll
            for (int n = 0; n < 4; ++n)
                acc[m][n] = __builtin_amdgcn_mfma_f32_16x16x32_bf16(a[m], b[n], acc[m][n], 0, 0, 0);

        __syncthreads();
        cur ^= 1;
    }

    const size_t ldc = (size_t)Cc;
#pragma unroll
    for (int m = 0; m < 4; ++m) {
#pragma unroll
        for (int n = 0; n < 4; ++n) {
            const int col = colBlk + wn + n * 16 + l15;
#pragma unroll
            for (int r = 0; r < 4; ++r) {
                const int row = rowBlk + wm + m * 16 + l4 * 4 + r;
                float v = acc[m][n][r];
                v = v > 0.f ? v : (expf(v) - 1.f);
                C[(size_t)row * ldc + col] = v;
            }
        }
    }
}

// in-place masked softmax over rows of Bm [NN x MM] (fp32); masked entries
// hold -1e9. Also emits a bf16 (RTNE) copy of the probs for the PV GEMM.
__global__ __launch_bounds__(256) void softmax_rows_f32(
    float* __restrict__ Bm, u16* __restrict__ B16)
{
    const int row = blockIdx.x;
    const int tid = threadIdx.x;
    const int lane = tid & 63;
    const int wid = tid >> 6;
    float4* rp = reinterpret_cast<float4*>(Bm + (size_t)row * MM);  // 1024 float4

    float4 q[4];
#pragma unroll
    for (int i = 0; i < 4; ++i) q[i] = rp[i * 256 + tid];           // coalesced
    float v[16];
#pragma unroll
    for (int i = 0; i < 4; ++i) {
        v[4 * i + 0] = q[i].x; v[4 * i + 1] = q[i].y;
        v[4 * i + 2] = q[i].z; v[4 * i + 3] = q[i].w;
    }

    float mx = -3e38f;
#pragma unroll
    for (int i = 0; i < 16; ++i) mx = fmaxf(mx, v[i]);
#pragma unroll
    for (int off = 32; off >= 1; off >>= 1) mx = fmaxf(mx, __shfl_xor(mx, off));
    __shared__ float red[4];
    if (lane == 0) red[wid] = mx;
    __syncthreads();
    mx = fmaxf(fmaxf(red[0], red[1]), fmaxf(red[2], red[3]));
    __syncthreads();

    float e[16];
    float s = 0.f;
#pragma unroll
    for (int i = 0; i < 16; ++i) { e[i] = expf(v[i] - mx); s += e[i]; }
#pragma unroll
    for (int off = 32; off >= 1; off >>= 1) s += __shfl_xor(s, off);
    if (lane == 0) red[wid] = s;
    __syncthreads();
    s = red[0] + red[1] + red[2] + red[3];
    const float inv = (mx > -1e8f && s > 0.f) ? (1.0f / s) : 0.f;   // all-masked row -> 0

    ushort4* hp = reinterpret_cast<ushort4*>(B16 + (size_t)row * MM);
#pragma unroll
    for (int i = 0; i < 4; ++i) {
        q[i].x = e[4 * i + 0] * inv; q[i].y = e[4 * i + 1] * inv;
        q[i].z = e[4 * i + 2] * inv; q[i].w = e[4 * i + 3] * inv;
        rp[i * 256 + tid] = q[i];
        ushort4 h;
        h.x = f2bf_rtne(q[i].x); h.y = f2bf_rtne(q[i].y);
        h.z = f2bf_rtne(q[i].z); h.w = f2bf_rtne(q[i].w);
        hp[i * 256 + tid] = h;
    }
}

extern "C" void kernel_launch(void* const* d_in, const int* in_sizes, int n_in,
                              void* d_out, int out_size, void* d_ws, size_t ws_size,
                              hipStream_t stream)
{
    (void)d_ws; (void)ws_size;

    float* O = (float*)d_out;                    // [NN*DD] output 0 (fp32)
    bool ok_sizes = (n_in == 5)
        && in_sizes[0] == NN * DD && in_sizes[1] == MM * DD
        && in_sizes[2] == NN * MM
        && in_sizes[3] == DD * DD && in_sizes[4] == DD * DD;
    if (!ok_sizes) { sentinel_kernel<<<1, 64, 0, stream>>>(O, 1e6f); return; }
    if (out_size != NN * DD + NN * MM) { sentinel_kernel<<<1, 64, 0, stream>>>(O, 2e6f); return; }

    const float* x  = (const float*)d_in[0];   // [NN, DD]
    const float* er = (const float*)d_in[1];   // [MM, DD]
    const int*   Hm = (const int*)d_in[2];     // [NN, MM]
    const float* We = (const float*)d_in[3];   // [DD, DD]
    const float* Wn = (const float*)d_in[4];   // [DD, DD]

    float* Bo = O + (size_t)NN * DD;             // [NN*MM] output 1 (fp32)

    // Scratch (no d_ws; inputs restored by harness each launch):
    //   input split planes -> Bo region (92 MB <= 256 MB; all dead by step 4)
    //   hn hi/lo planes    -> O[0:64MB) (dead before step 6 writes O)
    //   he hi+lo, heT hi   -> x's buffer (24 MB <= 64 MB; x dead after splits)
    //   B bf16 probs       -> Hm's buffer (128 MB <= 256 MB; Hm dead after step 4)
    u16* xs_h  = (u16*)Bo;
    u16* xs_l  = xs_h  + (size_t)NN * DD;
    u16* ers_h = xs_l  + (size_t)NN * DD;
    u16* ers_l = ers_h + (size_t)MM * DD;
    u16* wes_h = ers_l + (size_t)MM * DD;
    u16* wes_l = wes_h + (size_t)DD * DD;
    u16* wns_h = wes_l + (size_t)DD * DD;
    u16* wns_l = wns_h + (size_t)DD * DD;

    u16* hn_h  = (u16*)O;
    u16* hn_l  = hn_h + (size_t)NN * DD;
    u16* he_h  = (u16*)d_in[0];
    u16* he_l  = he_h + (size_t)MM * DD;
    u16* heT_h = he_l + (size_t)MM * DD;
    u16* B16   = (u16*)d_in[2];

    dim3 blk(256);
    // 0. one-time exact splits of all fp32 inputs (last reads of x/er/We/Wn)
    split_f32<<<dim3(2048), blk, 0, stream>>>(x,  xs_h,  xs_l,  (long)NN * DD / 4);
    split_f32<<<dim3(1024), blk, 0, stream>>>(er, ers_h, ers_l, (long)MM * DD / 4);
    split_f32<<<dim3(512),  blk, 0, stream>>>(We, wes_h, wes_l, (long)DD * DD / 4);
    split_f32<<<dim3(512),  blk, 0, stream>>>(Wn, wns_h, wns_l, (long)DD * DD / 4);
    // 1. hn = x @ Wn^T -> split planes in O[0:64MB)
    gemm_ps3<EPI_SPLIT><<<dim3(DD / 128, NN / 128), blk, 0, stream>>>(
        xs_h, xs_l, wns_h, wns_l, hn_h, hn_l, nullptr, nullptr, DD, DD);
    // 2. he = e_repr @ We^T -> split planes in x buffer
    gemm_ps3<EPI_SPLIT><<<dim3(DD / 128, MM / 128), blk, 0, stream>>>(
        ers_h, ers_l, wes_h, wes_l, he_h, he_l, nullptr, nullptr, DD, DD);
    // 3. heT = We @ e_repr^T (= he^T) -> hi plane only (feeds bf16 PV GEMM)
    gemm_ps3<EPI_SPLITH><<<dim3(MM / 128, DD / 128), blk, 0, stream>>>(
        wes_h, wes_l, ers_h, ers_l, heT_h, nullptr, nullptr, nullptr, MM, DD);
    // 4. S = (hn @ he^T)/32, masked -> Bo (overwrites dead input splits;
    //    last use of Hm)
    gemm_ps3<EPI_MASK><<<dim3(MM / 128, NN / 128), blk, 0, stream>>>(
        hn_h, hn_l, he_h, he_l, nullptr, nullptr, Bo, Hm, MM, DD);
    // 5. B = softmax(S) * mask, in place (fp32) + bf16 copy into Hm buffer
    softmax_rows_f32<<<dim3(NN), blk, 0, stream>>>(Bo, B16);
    // 6. out = elu(B16 @ heT^T) -> O[0:64MB) (hn planes dead)
    gemm_bf16_elu<<<dim3(DD / 128, NN / 128), blk, 0, stream>>>(B16, heT_h, O, DD, MM);
}